// Round 8
// baseline (457.701 us; speedup 1.0000x reference)
//
#include <hip/hip_runtime.h>
#include <hip/hip_bf16.h>

namespace {

constexpr int Sseq = 2048;
constexpr int NH   = 16;
constexpr int HD   = 64;
constexpr int ROW  = NH * HD;             // 1024 floats between consecutive s
constexpr int BN   = 64;                  // kv rows per tile
constexpr int NT   = Sseq / BN;           // 32 kv tiles
constexpr size_t IMG_BYTES = 16384;       // per (bh,tile): K-image 8KB + V^T-image 8KB
constexpr size_t WS_NEED   = (size_t)32 * NT * IMG_BYTES;   // 16 MiB
constexpr float QSCALE = 0.18033688011112042f; // (1/8) * log2(e)

typedef __bf16 bf16_t;
typedef __attribute__((ext_vector_type(8))) bf16_t bf16x8;
typedef __attribute__((ext_vector_type(4))) float f32x4;
typedef __attribute__((ext_vector_type(16))) float f32x16;
typedef __attribute__((ext_vector_type(2))) unsigned int u32x2;
typedef __attribute__((ext_vector_type(4))) unsigned int u32x4;

union Frag { bf16x8 v; unsigned int u[4]; };

__device__ inline unsigned int pkbf(float a, float b) {
  union { __hip_bfloat162 h; unsigned int u; } x;
  x.h = __float22bfloat162_rn(make_float2(a, b));
  return x.u;
}

// R8: R5/R6/R7 all plateaued 62-87us -> the barrier-coupled LDS round-trip
// chain was the floor, not any pipe. This round: barrier-free, LDS-free,
// wave-independent. One wave owns 32 q rows; K/V frags read straight from
// the prepped global images (L2-resident, L1-shared by the block's 4 waves
// of the same bh); P C->A transform via __shfl_xor(32) register exchange
// (for 32x32 MFMA the transform is exactly a half-wave swap of reg-quads).
// 2-deep register pipeline across tiles. No __syncthreads in the main loop.
//
// Layouts (guide-verified): A[m=lane&31][k=(lane>>5)*8+j];
// B[k=(lane>>5)*8+j][n=lane&31]; C/D col=lane&31,
// row=(reg&3)+8*(reg>>2)+4*(lane>>5).

// ---------------- prep: K,V fp32 -> pre-swizzled bf16 tile images ----------
__global__ __launch_bounds__(256)
void prep_kv(const float* __restrict__ K, const float* __restrict__ V,
             unsigned short* __restrict__ ws) {
  const int id  = blockIdx.x;
  const int bh  = id & 31;                // XCD = id % 8
  const int t   = id >> 5;                // kv tile
  const int tid = threadIdx.x;

  const size_t base = (size_t)(bh >> 4) * Sseq * ROW + (size_t)(bh & 15) * HD
                    + (size_t)(t * BN) * ROW;
  const float* kb = K + base;
  const float* vb = V + base;

  unsigned short* gK = (unsigned short*)((char*)ws + (size_t)(bh * NT + t) * IMG_BYTES);
  unsigned short* gV = gK + 4096;

  { // K image: [kv 64][d 64] bf16, 16B-chunk XOR swizzle ^ (kv&7)
    const int kr = tid >> 2;
    const int kd = (tid & 3) * 16;
    const float* p = kb + (size_t)kr * ROW + kd;
    f32x4 x0 = *(const f32x4*)(p);
    f32x4 x1 = *(const f32x4*)(p + 4);
    f32x4 x2 = *(const f32x4*)(p + 8);
    f32x4 x3 = *(const f32x4*)(p + 12);
    int c0 = ((tid & 3) * 2) ^ (kr & 7);
    int c1 = ((tid & 3) * 2 + 1) ^ (kr & 7);
    u32x4 w0, w1;
    w0.x = pkbf(x0[0], x0[1]); w0.y = pkbf(x0[2], x0[3]);
    w0.z = pkbf(x1[0], x1[1]); w0.w = pkbf(x1[2], x1[3]);
    w1.x = pkbf(x2[0], x2[1]); w1.y = pkbf(x2[2], x2[3]);
    w1.z = pkbf(x3[0], x3[1]); w1.w = pkbf(x3[2], x3[3]);
    *(u32x4*)(gK + kr * 64 + c0 * 8) = w0;
    *(u32x4*)(gK + kr * 64 + c1 * 8) = w1;
  }
  { // V^T image: [d 64][kv 64] bf16, swizzle ^ (d&7)
    const int n4 = (tid & 15) * 4;
    const int d4 = (tid >> 4) * 4;
    const float* p = vb + (size_t)n4 * ROW + d4;
    f32x4 r0 = *(const f32x4*)(p);
    f32x4 r1 = *(const f32x4*)(p + ROW);
    f32x4 r2 = *(const f32x4*)(p + 2 * ROW);
    f32x4 r3 = *(const f32x4*)(p + 3 * ROW);
    #pragma unroll
    for (int i = 0; i < 4; ++i) {
      int d = d4 + i;
      int chunk = (n4 >> 3) ^ (d & 7);
      u32x2 val; val.x = pkbf(r0[i], r1[i]); val.y = pkbf(r2[i], r3[i]);
      *(u32x2*)(gV + d * 64 + chunk * 8 + (n4 & 7)) = val;
    }
  }
}

// ---------------- main: wave-independent, barrier-free, LDS-free ----------
__global__ __launch_bounds__(256)
void fa_main(const float* __restrict__ Q, const unsigned short* __restrict__ ws,
             float* __restrict__ O) {
  const int blk  = blockIdx.x;
  const int bh   = blk & 31;              // XCD = blk % 8; 4 waves share bh -> L1 reuse
  const int tid  = threadIdx.x;
  const int wave = tid >> 6;
  const int lane = tid & 63;
  const int l31  = lane & 31;
  const int h    = lane >> 5;
  const int qt   = (blk >> 5) * 4 + wave; // 0..63: this wave's 32-q tile

  const size_t base = (size_t)(bh >> 4) * Sseq * ROW + (size_t)(bh & 15) * HD;
  const float* qb = Q + base;
  float*       ob = O + base;
  const char*  imgs = (const char*)ws + (size_t)bh * NT * IMG_BYTES;

  const int qrow0 = qt * 32;

  // Q B-frags: B[k=d=f*16+h*8+j][n=q=l31], pre-scaled by (1/8)*log2e
  Frag qf[4];
  {
    const float* qp = qb + (size_t)(qrow0 + l31) * ROW + h * 8;
    #pragma unroll
    for (int f = 0; f < 4; ++f) {
      f32x4 a = *(const f32x4*)(qp + f * 16);
      f32x4 b = *(const f32x4*)(qp + f * 16 + 4);
      qf[f].u[0] = pkbf(a[0] * QSCALE, a[1] * QSCALE);
      qf[f].u[1] = pkbf(a[2] * QSCALE, a[3] * QSCALE);
      qf[f].u[2] = pkbf(b[0] * QSCALE, b[1] * QSCALE);
      qf[f].u[3] = pkbf(b[2] * QSCALE, b[3] * QSCALE);
    }
  }

  f32x16 oacc[2] = {};   // [mt: d-half], C: col=q=l31, row=d_local
  float lsum = 0.f;

  // frag double-buffer across tiles
  Frag ka[2][2][4];      // [buf][kh: kv-half][f: d-chunk]
  Frag va[2][2][2][2];   // [buf][mt: d-half][kh][k2: kv-16-group]

  auto ldTile = [&](int t, int buf) {
    const unsigned short* img = (const unsigned short*)(imgs + (size_t)t * IMG_BYTES);
    const unsigned short* gV  = img + 4096;
    #pragma unroll
    for (int kh = 0; kh < 2; ++kh) {
      int r = kh * 32 + l31;
      const unsigned short* rowp = img + r * 64;
      #pragma unroll
      for (int f = 0; f < 4; ++f) {
        int c = (2 * f + h) ^ (r & 7);
        ka[buf][kh][f].v = *(const bf16x8*)(rowp + c * 8);
      }
    }
    #pragma unroll
    for (int mt = 0; mt < 2; ++mt) {
      int d = mt * 32 + l31;
      const unsigned short* rowp = gV + d * 64;
      #pragma unroll
      for (int kh = 0; kh < 2; ++kh)
        #pragma unroll
        for (int k2 = 0; k2 < 2; ++k2) {
          int c = (4 * kh + 2 * k2 + h) ^ (d & 7);
          va[buf][mt][kh][k2].v = *(const bf16x8*)(rowp + c * 8);
        }
    }
  };

  ldTile(0, 0);

  for (int t = 0; t < NT; ++t) {
    const int cur = t & 1;
    if (t + 1 < NT) ldTile(t + 1, cur ^ 1);   // issue next-tile loads early

    #pragma unroll
    for (int kh = 0; kh < 2; ++kh) {
      // S^T(32kv x 32q) = K·Q^T, k=64
      f32x16 s = {};
      #pragma unroll
      for (int f = 0; f < 4; ++f)
        s = __builtin_amdgcn_mfma_f32_32x32x16_bf16(ka[cur][kh][f].v, qf[f].v, s, 0, 0, 0);

      float e[16];
      float ls = 0.f;
      #pragma unroll
      for (int i = 0; i < 16; ++i) { e[i] = __builtin_amdgcn_exp2f(s[i]); ls += e[i]; }
      lsum += ls;

      // pack: pk[c2'][b] covers kv_local = 4*(2*c2'+h) + (2b..2b+1)
      unsigned int pk[4][2];
      #pragma unroll
      for (int c2 = 0; c2 < 4; ++c2) {
        pk[c2][0] = pkbf(e[4 * c2],     e[4 * c2 + 1]);
        pk[c2][1] = pkbf(e[4 * c2 + 2], e[4 * c2 + 3]);
      }

      // half-wave exchange: send quads {1-h, 3-h}; receive partner's {h, 2+h}
      unsigned int s0 = h ? pk[0][0] : pk[1][0];
      unsigned int s1 = h ? pk[0][1] : pk[1][1];
      unsigned int s2 = h ? pk[2][0] : pk[3][0];
      unsigned int s3 = h ? pk[2][1] : pk[3][1];
      unsigned int r0 = (unsigned int)__shfl_xor((int)s0, 32, 64);
      unsigned int r1 = (unsigned int)__shfl_xor((int)s1, 32, 64);
      unsigned int r2 = (unsigned int)__shfl_xor((int)s2, 32, 64);
      unsigned int r3 = (unsigned int)__shfl_xor((int)s3, 32, 64);

      // O^T += V^T · P^T
      #pragma unroll
      for (int k2 = 0; k2 < 2; ++k2) {
        unsigned int own0 = pk[2 * k2 + h][0], own1 = pk[2 * k2 + h][1];
        unsigned int par0 = k2 ? r2 : r0,      par1 = k2 ? r3 : r1;
        Frag pf;
        pf.u[0] = h ? par0 : own0;   // k-half from hs=0 lane
        pf.u[1] = h ? par1 : own1;
        pf.u[2] = h ? own0 : par0;   // k-half from hs=1 lane
        pf.u[3] = h ? own1 : par1;
        #pragma unroll
        for (int mt = 0; mt < 2; ++mt)
          oacc[mt] = __builtin_amdgcn_mfma_f32_32x32x16_bf16(
              va[cur][mt][kh][k2].v, pf.v, oacc[mt], 0, 0, 0);
      }
    }
  }

  // epilogue: l(q=l31) = own-half sum + partner-half sum; normalize; store
  lsum += __shfl_xor(lsum, 32, 64);
  const float r = 1.0f / lsum;
  float* op = ob + (size_t)(qrow0 + l31) * ROW;
  #pragma unroll
  for (int mt = 0; mt < 2; ++mt)
    #pragma unroll
    for (int g = 0; g < 4; ++g) {
      int d0 = mt * 32 + 8 * g + 4 * h;       // row = (reg&3)+8g+4h
      f32x4 o;
      o[0] = oacc[mt][4 * g]     * r;
      o[1] = oacc[mt][4 * g + 1] * r;
      o[2] = oacc[mt][4 * g + 2] * r;
      o[3] = oacc[mt][4 * g + 3] * r;
      *(f32x4*)(op + d0) = o;
    }
}

// ---------------- fallback (R5 kernel) if ws too small --------------------
__global__ __launch_bounds__(256)
void fa_fwd_fb(const float* __restrict__ Q, const float* __restrict__ K,
               const float* __restrict__ V, float* __restrict__ O) {
  constexpr int BMf = 128, MT = 2;
  const int id   = blockIdx.x;
  const int bh   = id & 31;
  const int qblk = id >> 5;
  const int tid  = threadIdx.x;
  const int wave = tid >> 6;
  const int lane = tid & 63;
  const int qd   = lane >> 4;
  const int lm   = lane & 15;

  const size_t base = (size_t)(bh >> 4) * Sseq * ROW + (size_t)(bh & 15) * HD;
  const float* qb = Q + base;
  const float* kb = K + base;
  const float* vb = V + base;
  float*       ob = O + base;

  __shared__ __align__(16) unsigned short KT[2][HD * 64];
  __shared__ __align__(16) unsigned short VT[2][HD * 64];
  __shared__ __align__(16) unsigned short PBf[4][MT][16 * 64];

  const int qrow0 = qblk * BMf + wave * (MT * 16);

  Frag qf[MT][2];
  for (int mt = 0; mt < MT; ++mt) {
    const float* qp = qb + (size_t)(qrow0 + mt * 16 + lm) * ROW;
    for (int ks = 0; ks < 2; ++ks) {
      f32x4 a = *(const f32x4*)(qp + ks * 32 + qd * 8);
      f32x4 c = *(const f32x4*)(qp + ks * 32 + qd * 8 + 4);
      qf[mt][ks].u[0] = pkbf(a[0] * QSCALE, a[1] * QSCALE);
      qf[mt][ks].u[1] = pkbf(a[2] * QSCALE, a[3] * QSCALE);
      qf[mt][ks].u[2] = pkbf(c[0] * QSCALE, c[1] * QSCALE);
      qf[mt][ks].u[3] = pkbf(c[2] * QSCALE, c[3] * QSCALE);
    }
  }

  f32x4 oacc[MT][4] = {};
  float lsum[MT] = {};

  const int kr = tid >> 2;
  const int kd = (tid & 3) * 16;
  const int n4 = (tid & 15) * 4;
  const int d4 = (tid >> 4) * 4;

  const float* kp = kb + (size_t)kr * ROW + kd;
  const float* vp = vb + (size_t)n4 * ROW + d4;

  f32x4 kx0 = *(const f32x4*)(kp);
  f32x4 kx1 = *(const f32x4*)(kp + 4);
  f32x4 kx2 = *(const f32x4*)(kp + 8);
  f32x4 kx3 = *(const f32x4*)(kp + 12);
  f32x4 vx0 = *(const f32x4*)(vp);
  f32x4 vx1 = *(const f32x4*)(vp + ROW);
  f32x4 vx2 = *(const f32x4*)(vp + 2 * ROW);
  f32x4 vx3 = *(const f32x4*)(vp + 3 * ROW);

  for (int t = 0; t < NT; ++t) {
    unsigned short* kt = KT[t & 1];
    unsigned short* vt = VT[t & 1];
    {
      int c0 = ((tid & 3) * 2) ^ (kr & 7);
      int c1 = ((tid & 3) * 2 + 1) ^ (kr & 7);
      u32x4 w0, w1;
      w0.x = pkbf(kx0[0], kx0[1]); w0.y = pkbf(kx0[2], kx0[3]);
      w0.z = pkbf(kx1[0], kx1[1]); w0.w = pkbf(kx1[2], kx1[3]);
      w1.x = pkbf(kx2[0], kx2[1]); w1.y = pkbf(kx2[2], kx2[3]);
      w1.z = pkbf(kx3[0], kx3[1]); w1.w = pkbf(kx3[2], kx3[3]);
      *(u32x4*)(kt + kr * 64 + c0 * 8) = w0;
      *(u32x4*)(kt + kr * 64 + c1 * 8) = w1;
    }
    {
      #pragma unroll
      for (int i = 0; i < 4; ++i) {
        int d = d4 + i;
        int chunk = (n4 >> 3) ^ (d & 7);
        u32x2 val; val.x = pkbf(vx0[i], vx1[i]); val.y = pkbf(vx2[i], vx3[i]);
        *(u32x2*)(vt + d * 64 + chunk * 8 + (n4 & 7)) = val;
      }
    }
    __syncthreads();
    if (t + 1 < NT) {
      kp += BN * ROW; vp += BN * ROW;
      kx0 = *(const f32x4*)(kp);
      kx1 = *(const f32x4*)(kp + 4);
      kx2 = *(const f32x4*)(kp + 8);
      kx3 = *(const f32x4*)(kp + 12);
      vx0 = *(const f32x4*)(vp);
      vx1 = *(const f32x4*)(vp + ROW);
      vx2 = *(const f32x4*)(vp + 2 * ROW);
      vx3 = *(const f32x4*)(vp + 3 * ROW);
    }
    #pragma unroll
    for (int c = 0; c < 4; ++c) {
      Frag kf0, kf1;
      {
        int r = c * 16 + lm;
        int ch0 = (qd) ^ (lm & 7);
        int ch1 = (4 + qd) ^ (lm & 7);
        kf0.v = *(const bf16x8*)(kt + r * 64 + ch0 * 8);
        kf1.v = *(const bf16x8*)(kt + r * 64 + ch1 * 8);
      }
      #pragma unroll
      for (int mt = 0; mt < MT; ++mt) {
        f32x4 s = {};
        s = __builtin_amdgcn_mfma_f32_16x16x32_bf16(kf0.v, qf[mt][0].v, s, 0, 0, 0);
        s = __builtin_amdgcn_mfma_f32_16x16x32_bf16(kf1.v, qf[mt][1].v, s, 0, 0, 0);
        float e0 = __builtin_amdgcn_exp2f(s[0]);
        float e1 = __builtin_amdgcn_exp2f(s[1]);
        float e2 = __builtin_amdgcn_exp2f(s[2]);
        float e3 = __builtin_amdgcn_exp2f(s[3]);
        lsum[mt] += (e0 + e1) + (e2 + e3);
        int n = c * 16 + qd * 4;
        int chunk = (n >> 3) ^ (lm & 7);
        u32x2 val; val.x = pkbf(e0, e1); val.y = pkbf(e2, e3);
        *(u32x2*)(PBf[wave][mt] + lm * 64 + chunk * 8 + (n & 7)) = val;
      }
    }
    __threadfence_block();
    #pragma unroll
    for (int ks = 0; ks < 2; ++ks) {
      bf16x8 pfr[MT];
      #pragma unroll
      for (int mt = 0; mt < MT; ++mt) {
        int chunk = (ks * 4 + qd) ^ (lm & 7);
        pfr[mt] = *(const bf16x8*)(PBf[wave][mt] + lm * 64 + chunk * 8);
      }
      #pragma unroll
      for (int dt = 0; dt < 4; ++dt) {
        int d = dt * 16 + lm;
        int chunk = (ks * 4 + qd) ^ (d & 7);
        bf16x8 vf = *(const bf16x8*)(vt + d * 64 + chunk * 8);
        #pragma unroll
        for (int mt = 0; mt < MT; ++mt)
          oacc[mt][dt] = __builtin_amdgcn_mfma_f32_16x16x32_bf16(vf, pfr[mt], oacc[mt][dt], 0, 0, 0);
      }
    }
  }

  #pragma unroll
  for (int mt = 0; mt < MT; ++mt) {
    float l = lsum[mt];
    l += __shfl_xor(l, 16, 64);
    l += __shfl_xor(l, 32, 64);
    float r = 1.0f / l;
    float* op = ob + (size_t)(qrow0 + mt * 16 + lm) * ROW + qd * 4;
    #pragma unroll
    for (int dt = 0; dt < 4; ++dt) {
      f32x4 o = oacc[mt][dt];
      o[0] *= r; o[1] *= r; o[2] *= r; o[3] *= r;
      *(f32x4*)(op + dt * 16) = o;
    }
  }
}

} // namespace

extern "C" void kernel_launch(void* const* d_in, const int* in_sizes, int n_in,
                              void* d_out, int out_size, void* d_ws, size_t ws_size,
                              hipStream_t stream) {
  const float* q = (const float*)d_in[0];
  const float* k = (const float*)d_in[1];
  const float* v = (const float*)d_in[2];
  float* o = (float*)d_out;
  (void)in_sizes; (void)n_in; (void)out_size;
  if (ws_size >= WS_NEED) {
    hipLaunchKernelGGL(prep_kv, dim3(32 * NT), dim3(256), 0, stream,
                       k, v, (unsigned short*)d_ws);
    // 512 blocks x 4 waves = 2048 independent waves (32 bh x 64 q-tiles)
    hipLaunchKernelGGL(fa_main, dim3(512), dim3(256), 0, stream,
                       q, (const unsigned short*)d_ws, o);
  } else {
    hipLaunchKernelGGL(fa_fwd_fb, dim3(2 * NH * (Sseq / 128)), dim3(256), 0, stream,
                       q, k, v, o);
  }
}